// Round 19
// baseline (157.245 us; speedup 1.0000x reference)
//
#include <hip/hip_runtime.h>

// Decoder: 2-layer LSTM (H=32) + MLP (96), B=16384, 25 steps.
// R19 = R17 (pure register recurrence, zero barriers/fences in loop) with
// ET 16->8: grid 2048 single-wave blocks = 2 waves/SIMD = 2 INDEPENDENT
// fence-free chains per SIMD (the only untested cell of the chains x sync
// matrix; barrier'd family gained +20% from 1->2 chains). Lanes 8-15 mirror
// lanes 0-7; stores masked lr<8. Otherwise byte-identical to R17.

#define PRED 25
#define BATCH 16384
#define ET    8

typedef unsigned short u16;
typedef unsigned int   u32;
typedef __attribute__((ext_vector_type(8))) short bf16x8;
typedef __attribute__((ext_vector_type(4))) float f32x4;

#define LOG2E  1.44269504088896340736f
#define LOG2E2 2.88539008177792681472f

__device__ __forceinline__ float rcp_(float x){ return __builtin_amdgcn_rcpf(x); }
__device__ __forceinline__ float ex2(float x){ return __builtin_amdgcn_exp2f(x); }
__device__ __forceinline__ float sigm2(float xp){ return rcp_(1.0f + ex2(-xp)); }
__device__ __forceinline__ float tanh2(float xp){ return 1.0f - 2.0f*rcp_(ex2(xp) + 1.0f); }

__device__ __forceinline__ u16 f2b(float f){
  __bf16 b = (__bf16)f;
  return __builtin_bit_cast(u16, b);
}

__device__ __forceinline__ float act_h(f32x4 g, float& c){
  float ig = sigm2(g[0]);
  float fg = sigm2(g[1]);
  float gg = tanh2(g[2]);
  float og = sigm2(g[3]);
  c = fmaf(fg, c, ig*gg);
  return og * tanh2(c*LOG2E2);
}

__device__ __forceinline__ bf16x8 packh(const float* h){
  union{bf16x8 v; u16 s[8];} r;
  #pragma unroll
  for (int j = 0; j < 8; ++j) r.s[j] = f2b(h[j]);
  return r.v;
}

// ---------- prep: ws[0..4095] = Wcomb = Wih0 @ Wmlp ; ws[4096..4223] = bcomb ----------
extern "C" __global__ void prep_kernel(const float* __restrict__ Wih0,
                                       const float* __restrict__ Wmlp,
                                       const float* __restrict__ bih0,
                                       const float* __restrict__ bhh0,
                                       const float* __restrict__ bmlp,
                                       float* __restrict__ ws){
  int idx = blockIdx.x*256 + threadIdx.x;
  if (idx < 4096){
    int g = idx >> 5, u = idx & 31;
    const float* wr = Wih0 + g*96;
    const float* wc = Wmlp + u;
    float a = 0.f;
    #pragma unroll 8
    for (int p = 0; p < 96; ++p) a = fmaf(wr[p], wc[p*32], a);
    ws[idx] = a;
  } else if (idx < 4224){
    int g = idx - 4096;
    const float* wr = Wih0 + g*96;
    float a = bih0[g] + bhh0[g];
    #pragma unroll 8
    for (int p = 0; p < 96; ++p) a = fmaf(wr[p], bmlp[p], a);
    ws[idx] = a;
  }
}

// LDS constants only (staged once; never written in the loop -> no fences)
struct __align__(16) SM {
  float b1L[128];     // [i*16 + kq*4 + r], exp2-scaled
  float bcombL[128];  // [i*16 + kq*4 + r], exp2-scaled
  float bmL[96];      // [i*16 + kq*4 + r], natural
  u16   awmL[6*64*8]; // MLP A-frags, pi-K, [i][lane][8]
};

extern "C" __global__ __launch_bounds__(64, 2)
void decoder_kernel(const float* __restrict__ obs,  const float* __restrict__ lat,
                    const float* __restrict__ Wfc,  const float* __restrict__ bfc,
                    const float* __restrict__ Wih0, const float* __restrict__ Whh0,
                    const float* __restrict__ bih0, const float* __restrict__ bhh0,
                    const float* __restrict__ Wih1, const float* __restrict__ Whh1,
                    const float* __restrict__ bih1, const float* __restrict__ bhh1,
                    const float* __restrict__ Wmlp, const float* __restrict__ bmlp,
                    const float* __restrict__ ws,   float* __restrict__ out)
{
  __shared__ SM sm;
  const int l  = threadIdx.x;
  const int lr = l & 15;      // frag row
  const int kq = l >> 4;      // k-quad
  const int el = lr & 7;      // element (lanes 8-15 mirror 0-7)
  const int ebase = blockIdx.x * ET;

  // ---- stage LDS constants ----
  for (int v = l; v < 128; v += 64){
    int i = v >> 4, kqq = (v >> 2) & 3, r = v & 3;
    int u = i*4 + kqq, g = r*32 + u;
    float sc = (r == 2) ? LOG2E2 : LOG2E;
    sm.b1L[v]    = (bih1[g] + bhh1[g])*sc;
    sm.bcombL[v] = ws[4096 + g]*sc;
  }
  for (int v = l; v < 96; v += 64) sm.bmL[v] = bmlp[v];
  #pragma unroll
  for (int i = 0; i < 6; ++i){
    union{bf16x8 v; u16 s[8];} fr;
    #pragma unroll
    for (int j = 0; j < 8; ++j) fr.s[j] = f2b(Wmlp[(i*16 + lr)*32 + 4*j + kq]);
    *(bf16x8*)&sm.awmL[(i*64 + l)*8] = fr.v;
  }

  // ---- persistent weight frags (pi-K: pos kq*8+j <- col 4j+kq; gate-permuted M) ----
  bf16x8 wcombf[8], whh0f[8], wih1f[8], whh1f[8];
  #pragma unroll
  for (int i = 0; i < 8; ++i){
    int vg = i*16 + lr;
    int g  = (vg & 3)*32 + (vg >> 2);
    float sc = ((vg & 3) == 2) ? LOG2E2 : LOG2E;
    union{bf16x8 v; u16 s[8];} a, b, c, d;
    #pragma unroll
    for (int j = 0; j < 8; ++j){
      int col = 4*j + kq;
      a.s[j] = f2b(ws[g*32 + col]*sc);
      b.s[j] = f2b(Whh0[g*32 + col]*sc);
      c.s[j] = f2b(Wih1[g*32 + col]*sc);
      d.s[j] = f2b(Whh1[g*32 + col]*sc);
    }
    wcombf[i] = a.v; whh0f[i] = b.v; wih1f[i] = c.v; whh1f[i] = d.v;
  }

  // ---- h_init = Wfc@latent + bfc, pi-packed (slot j = unit 4j+kq), e = el ----
  float hinit[8];
  {
    const float* lp = lat + (size_t)(ebase + el)*16;
    float lv[16];
    #pragma unroll
    for (int j = 0; j < 16; ++j) lv[j] = lp[j];
    #pragma unroll
    for (int j = 0; j < 8; ++j){
      int u = 4*j + kq;
      const float* wf = Wfc + u*16;
      float a = bfc[u];
      #pragma unroll
      for (int p = 0; p < 16; ++p) a = fmaf(wf[p], lv[p], a);
      hinit[j] = a;
    }
  }
  bf16x8 h1hf = packh(hinit);   // h1(-1) = h_init; also h0(-1) for peel

  float c0a[8] = {0,0,0,0,0,0,0,0};
  float c1a[8] = {0,0,0,0,0,0,0,0};

  __syncthreads();   // LDS constants visible (only sync in the kernel)

  // ---- peel: GEMM0(0) = Wih0.x0 (natural K) + Whh0.h_init + b00 ----
  bf16x8 h0f;
  {
    bf16x8 bx[3];
    const float* xr = obs + ((size_t)15*BATCH + ebase + el)*96;
    #pragma unroll
    for (int c = 0; c < 3; ++c){
      union{bf16x8 v; u16 s[8];} fr;
      const float* s8 = xr + c*32 + kq*8;
      #pragma unroll
      for (int j = 0; j < 8; ++j) fr.s[j] = f2b(s8[j]);
      bx[c] = fr.v;
    }
    float h0n[8];
    #pragma unroll
    for (int i = 0; i < 8; ++i){
      int vg = i*16 + lr;
      int g  = (vg & 3)*32 + (vg >> 2);
      float sc = ((vg & 3) == 2) ? LOG2E2 : LOG2E;
      int u = i*4 + kq;
      f32x4 acc;
      #pragma unroll
      for (int r = 0; r < 4; ++r){
        int gg = r*32 + u;
        acc[r] = (bih0[gg] + bhh0[gg])*((r == 2) ? LOG2E2 : LOG2E);
      }
      #pragma unroll
      for (int c = 0; c < 3; ++c){
        union{bf16x8 v; u16 s[8];} fr;
        const float* s8 = Wih0 + g*96 + c*32 + kq*8;
        #pragma unroll
        for (int j = 0; j < 8; ++j) fr.s[j] = f2b(s8[j]*sc);
        acc = __builtin_amdgcn_mfma_f32_16x16x32_bf16(fr.v, bx[c], acc, 0, 0, 0);
      }
      acc = __builtin_amdgcn_mfma_f32_16x16x32_bf16(whh0f[i], h1hf, acc, 0, 0, 0);
      h0n[i] = act_h(acc, c0a[i]);
    }
    h0f = packh(h0n);
  }

  #pragma unroll 1
  for (int t = 0; t < PRED; ++t){
    // ---- GEMM1(t): gates1 = b1 + Wih1.h0(t) + Whh1.h1(t-1) ----
    float h1n[8];
    #pragma unroll
    for (int i = 0; i < 8; ++i){
      f32x4 acc = *(const f32x4*)&sm.b1L[i*16 + kq*4];
      acc = __builtin_amdgcn_mfma_f32_16x16x32_bf16(wih1f[i], h0f,  acc, 0, 0, 0);
      acc = __builtin_amdgcn_mfma_f32_16x16x32_bf16(whh1f[i], h1hf, acc, 0, 0, 0);
      h1n[i] = act_h(acc, c1a[i]);
    }
    h1hf = packh(h1n);   // h1(t), pi-local
    // ---- MLP (off-chain): out[t] = bm + Wm.h1(t); masked f32x4 stores ----
    float* ob = out + (size_t)t*BATCH*96 + (size_t)(ebase + lr)*96;
    #pragma unroll
    for (int i = 0; i < 6; ++i){
      bf16x8 wmv = *(const bf16x8*)&sm.awmL[(i*64 + l)*8];
      f32x4 acc = *(const f32x4*)&sm.bmL[i*16 + kq*4];
      acc = __builtin_amdgcn_mfma_f32_16x16x32_bf16(wmv, h1hf, acc, 0, 0, 0);
      if (lr < ET) *(f32x4*)(ob + i*16 + kq*4) = acc;
    }
    // ---- GEMM0(t+1): gates0 = bcomb + Wcomb.h1(t) + Whh0.h0(t) ----
    if (t != PRED-1){
      float h0n[8];
      #pragma unroll
      for (int i = 0; i < 8; ++i){
        f32x4 acc = *(const f32x4*)&sm.bcombL[i*16 + kq*4];
        acc = __builtin_amdgcn_mfma_f32_16x16x32_bf16(wcombf[i], h1hf, acc, 0, 0, 0);
        acc = __builtin_amdgcn_mfma_f32_16x16x32_bf16(whh0f[i],  h0f,  acc, 0, 0, 0);
        h0n[i] = act_h(acc, c0a[i]);
      }
      h0f = packh(h0n);   // h0(t+1), pi-local
    }
  }
}

extern "C" void kernel_launch(void* const* d_in, const int* in_sizes, int n_in,
                              void* d_out, int out_size, void* d_ws, size_t ws_size,
                              hipStream_t stream){
  const float* obs  = (const float*)d_in[0];
  const float* lat  = (const float*)d_in[1];
  const float* Wfc  = (const float*)d_in[3];
  const float* bfc  = (const float*)d_in[4];
  const float* Wih0 = (const float*)d_in[5];
  const float* Whh0 = (const float*)d_in[6];
  const float* bih0 = (const float*)d_in[7];
  const float* bhh0 = (const float*)d_in[8];
  const float* Wih1 = (const float*)d_in[9];
  const float* Whh1 = (const float*)d_in[10];
  const float* bih1 = (const float*)d_in[11];
  const float* bhh1 = (const float*)d_in[12];
  const float* Wmlp = (const float*)d_in[13];
  const float* bmlp = (const float*)d_in[14];
  float* ws = (float*)d_ws;

  prep_kernel<<<dim3(17), dim3(256), 0, stream>>>(Wih0, Wmlp, bih0, bhh0, bmlp, ws);
  decoder_kernel<<<dim3(BATCH/ET), dim3(64), 0, stream>>>(
      obs, lat, Wfc, bfc, Wih0, Whh0, bih0, bhh0,
      Wih1, Whh1, bih1, bhh1, Wmlp, bmlp, ws, (float*)d_out);
}

// Round 20
// 71.357 us; speedup vs baseline: 2.2036x; 2.2036x over previous
//
#include <hip/hip_runtime.h>

// Decoder: 2-layer LSTM (H=32) + MLP (96), B=16384, 25 steps.
// FINAL = R18 (best measured: 71.6us, absmax 9.77e-4). 19-round campaign:
// 517 -> 71.6us. Structure: MFMA with step-invariant weights in VGPR frags,
// 2-wave m-split blocks x 2 independent 16-elem streams (2 blocks/CU),
// 3 lgkm-only barriers/step (no vmcnt drain in loop), exp2-prescaled gates,
// native bf16 cvt, h1 hi/lo split dropped, deduplicated parity-buffered
// state, deferred global stores. Plateau ~72us survived: barrier removal,
// fence removal, 2-phase Wcomb algebra, chains/SIMD 1-4 (TLP & ILP),
// occupancy 1-8 waves/SIMD, -25% VALU, -30% MFMA, unroll pinning, setprio.
// Remaining residual is a dependent-chain latency floor (~2.8us/step);
// counters show no memory/compute roofline (VALU 40%, MFMA 10%, HBM 20%).

#define PRED 25
#define BATCH 16384
#define ET    32    // 2 streams x 16
#define XROW  128   // xh row (u16): 0..95 x/curr (+pad to 128 for swizzle)
#define HROW  128   // hh row: 0..31 h0_A, 32..63 h0_B, 64..95 h1_A, 96..127 h1_B

typedef unsigned short u16;
typedef unsigned int   u32;
typedef __attribute__((ext_vector_type(8))) short bf16x8;
typedef __attribute__((ext_vector_type(4))) float f32x4;

#define LOG2E  1.44269504088896340736f
#define LOG2E2 2.88539008177792681472f

#define BARRIER_NOVM() asm volatile("s_waitcnt lgkmcnt(0)\ns_barrier" ::: "memory")

__device__ __forceinline__ float rcp_(float x){ return __builtin_amdgcn_rcpf(x); }
__device__ __forceinline__ float ex2(float x){ return __builtin_amdgcn_exp2f(x); }
__device__ __forceinline__ float sigm2(float xp){ return rcp_(1.0f + ex2(-xp)); }
__device__ __forceinline__ float tanh2(float xp){ return 1.0f - 2.0f*rcp_(ex2(xp) + 1.0f); }

// native bf16 convert (hardware cvt, RNE)
__device__ __forceinline__ u16 f2b(float f){
  __bf16 b = (__bf16)f;
  return __builtin_bit_cast(u16, b);
}
__device__ __forceinline__ u32 f2b2(float lo, float hi){
  return (u32)f2b(lo) | ((u32)f2b(hi) << 16);
}

struct __align__(16) SM {
  u16 xh[2][16*XROW];
  u16 hh[2][16*HROW];
};

__device__ __forceinline__ int swx(int e, int k){ return e*XROW + (k ^ ((e&7)<<3)); }
__device__ __forceinline__ int swh(int e, int k){ return e*HROW + (k ^ ((e&7)<<3)); }

__device__ __forceinline__ bf16x8 pack8s(const float* src, float s){
  union { bf16x8 v; u16 h[8]; } fr;
  #pragma unroll
  for (int j = 0; j < 8; ++j) fr.h[j] = f2b(src[j]*s);
  return fr.v;
}

extern "C" __global__ __launch_bounds__(128, 1)
void decoder_kernel(const float* __restrict__ obs,  const float* __restrict__ lat,
                    const float* __restrict__ Wfc,  const float* __restrict__ bfc,
                    const float* __restrict__ Wih0, const float* __restrict__ Whh0,
                    const float* __restrict__ bih0, const float* __restrict__ bhh0,
                    const float* __restrict__ Wih1, const float* __restrict__ Whh1,
                    const float* __restrict__ bih1, const float* __restrict__ bhh1,
                    const float* __restrict__ Wmlp, const float* __restrict__ bmlp,
                    float* __restrict__ out)
{
  __shared__ SM sm;
  const int tid = threadIdx.x;
  const int ebase = blockIdx.x * ET;
  const int mh = tid >> 6;        // wave 0..1 = m-half
  const int l  = tid & 63;
  const int lr = l & 15;          // row/col in 16-tile; e within stream
  const int kq = l >> 4;          // k-quad 0..3

  // ---- one-time LDS init: x = obs[15] (bf16); h_init -> h0/h1 parity 0 ----
  {
    int e = tid >> 2, c0 = (tid & 3)*24;
    int s = e >> 4, er = e & 15;
    const float* src = obs + ((size_t)(15*BATCH) + ebase + e)*96 + c0;
    #pragma unroll
    for (int j = 0; j < 12; ++j){
      float2 v = *(const float2*)(src + 2*j);
      *(u32*)&sm.xh[s][swx(er, c0 + 2*j)] = f2b2(v.x, v.y);
    }
  }
  {
    int u = tid & 31, e8 = (tid >> 5)*8;
    const float* wf = Wfc + u*16;
    float bb = bfc[u];
    #pragma unroll
    for (int r = 0; r < 8; ++r){
      int e = e8 + r, s = e >> 4, er = e & 15;
      const float* lp = lat + (size_t)(ebase + e)*16;
      float a = bb;
      #pragma unroll
      for (int j = 0; j < 16; ++j) a = fmaf(wf[j], lp[j], a);
      u16 hb = f2b(a);
      sm.hh[s][swh(er, 0 + u)]  = hb;   // h0 parity 0 (rows 0..31)
      sm.hh[s][swh(er, 64 + u)] = hb;   // h1 parity 0 (rows 64..95)
    }
  }

  // ---- preload weight A-fragments (step-invariant; gate rows pre-scaled) ----
  bf16x8 aw0[4][4];                 // GEMM0: 4 m-tiles x 4 k-chunks
  #pragma unroll
  for (int i = 0; i < 4; ++i){
    int vg = (mh*4 + i)*16 + lr;
    int g  = (vg & 3)*32 + (vg >> 2);     // gate-permuted row
    float sc = ((vg & 3) == 2) ? LOG2E2 : LOG2E;
    #pragma unroll
    for (int c = 0; c < 4; ++c){
      int k = c*32 + kq*8;
      const float* src = (k < 96) ? (Wih0 + g*96 + k) : (Whh0 + g*32 + (k - 96));
      aw0[i][c] = pack8s(src, sc);
    }
  }
  bf16x8 aw1[4][2];                 // GEMM1: K=64
  #pragma unroll
  for (int i = 0; i < 4; ++i){
    int vg = (mh*4 + i)*16 + lr;
    int g  = (vg & 3)*32 + (vg >> 2);
    float sc = ((vg & 3) == 2) ? LOG2E2 : LOG2E;
    #pragma unroll
    for (int c = 0; c < 2; ++c){
      int k = c*32 + kq*8;
      const float* src = (k < 32) ? (Wih1 + g*32 + k) : (Whh1 + g*32 + (k - 32));
      aw1[i][c] = pack8s(src, sc);
    }
  }
  bf16x8 awm[3];                    // MLP: 3 m-tiles per wave, K=32
  #pragma unroll
  for (int i = 0; i < 3; ++i){
    int o = (mh*3 + i)*16 + lr;
    awm[i] = pack8s(Wmlp + o*32 + kq*8, 1.0f);
  }

  // ---- biases (C-frag rows = kq*4 + r; scaled like their gate rows) ----
  f32x4 bias0v[4], bias1v[4];
  #pragma unroll
  for (int i = 0; i < 4; ++i){
    int u = (mh*4 + i)*4 + kq;
    #pragma unroll
    for (int r = 0; r < 4; ++r){
      int g = r*32 + u;
      float sc = (r == 2) ? LOG2E2 : LOG2E;
      bias0v[i][r] = (bih0[g] + bhh0[g])*sc;
      bias1v[i][r] = (bih1[g] + bhh1[g])*sc;
    }
  }
  f32x4 biasmv[3];
  #pragma unroll
  for (int i = 0; i < 3; ++i){
    int o0 = (mh*3 + i)*16 + kq*4;
    #pragma unroll
    for (int r = 0; r < 4; ++r) biasmv[i][r] = bmlp[o0 + r];
  }

  float c0s[2][4] = {{0,0,0,0},{0,0,0,0}};
  float c1s[2][4] = {{0,0,0,0},{0,0,0,0}};

  __syncthreads();   // init visible (one-time)

  f32x4 am[2][3];    // MLP results, stored to global AFTER B5

  #pragma unroll 1
  for (int t = 0; t < PRED; ++t){
    const int p = t & 1;
    // ---- P1: GEMM0 both streams; h0(t-1) from hh parity p ----
    f32x4 g0[2][4];
    __builtin_amdgcn_s_setprio(1);
    #pragma unroll
    for (int s = 0; s < 2; ++s){
      bf16x8 bx0 = *(const bf16x8*)&sm.xh[s][swx(lr, 0*32 + kq*8)];
      bf16x8 bx1 = *(const bf16x8*)&sm.xh[s][swx(lr, 1*32 + kq*8)];
      bf16x8 bx2 = *(const bf16x8*)&sm.xh[s][swx(lr, 2*32 + kq*8)];
      bf16x8 bx3 = *(const bf16x8*)&sm.hh[s][swh(lr, 32*p + kq*8)];
      #pragma unroll
      for (int i = 0; i < 4; ++i){
        f32x4 a = bias0v[i];
        a = __builtin_amdgcn_mfma_f32_16x16x32_bf16(aw0[i][0], bx0, a, 0, 0, 0);
        a = __builtin_amdgcn_mfma_f32_16x16x32_bf16(aw0[i][1], bx1, a, 0, 0, 0);
        a = __builtin_amdgcn_mfma_f32_16x16x32_bf16(aw0[i][2], bx2, a, 0, 0, 0);
        a = __builtin_amdgcn_mfma_f32_16x16x32_bf16(aw0[i][3], bx3, a, 0, 0, 0);
        g0[s][i] = a;
      }
    }
    __builtin_amdgcn_s_setprio(0);
    // ---- LSTM0 activation; h0(t) -> hh parity p^1 (single write) ----
    #pragma unroll
    for (int s = 0; s < 2; ++s)
      #pragma unroll
      for (int i = 0; i < 4; ++i){
        float ig = sigm2(g0[s][i][0]);
        float fg = sigm2(g0[s][i][1]);
        float gg = tanh2(g0[s][i][2]);
        float og = sigm2(g0[s][i][3]);
        float cn = fmaf(fg, c0s[s][i], ig*gg);
        c0s[s][i] = cn;
        int u = (mh*4 + i)*4 + kq;
        sm.hh[s][swh(lr, 32*(p^1) + u)] = f2b(og * tanh2(cn*LOG2E2));
      }
    BARRIER_NOVM();   // B2: h0(t) visible
    // ---- P3: GEMM1 both streams; h0(t) from p^1, h1(t-1) from 64+32p ----
    f32x4 g1[2][4];
    __builtin_amdgcn_s_setprio(1);
    #pragma unroll
    for (int s = 0; s < 2; ++s){
      bf16x8 bh0 = *(const bf16x8*)&sm.hh[s][swh(lr, 32*(p^1) + kq*8)];
      bf16x8 bh1 = *(const bf16x8*)&sm.hh[s][swh(lr, 64 + 32*p + kq*8)];
      #pragma unroll
      for (int i = 0; i < 4; ++i){
        f32x4 a = bias1v[i];
        a = __builtin_amdgcn_mfma_f32_16x16x32_bf16(aw1[i][0], bh0, a, 0, 0, 0);
        a = __builtin_amdgcn_mfma_f32_16x16x32_bf16(aw1[i][1], bh1, a, 0, 0, 0);
        g1[s][i] = a;
      }
    }
    __builtin_amdgcn_s_setprio(0);
    #pragma unroll
    for (int s = 0; s < 2; ++s)
      #pragma unroll
      for (int i = 0; i < 4; ++i){
        float ig = sigm2(g1[s][i][0]);
        float fg = sigm2(g1[s][i][1]);
        float gg = tanh2(g1[s][i][2]);
        float og = sigm2(g1[s][i][3]);
        float cn = fmaf(fg, c1s[s][i], ig*gg);
        c1s[s][i] = cn;
        int u = (mh*4 + i)*4 + kq;
        sm.hh[s][swh(lr, 64 + 32*(p^1) + u)] = f2b(og * tanh2(cn*LOG2E2));
      }
    BARRIER_NOVM();   // B4: h1(t) visible
    // ---- P4: MLP both streams (bf16 h1 only); feedback next x to xh ----
    __builtin_amdgcn_s_setprio(1);
    #pragma unroll
    for (int s = 0; s < 2; ++s){
      bf16x8 bmh = *(const bf16x8*)&sm.hh[s][swh(lr, 64 + 32*(p^1) + kq*8)];
      #pragma unroll
      for (int i = 0; i < 3; ++i){
        f32x4 a = biasmv[i];
        a = __builtin_amdgcn_mfma_f32_16x16x32_bf16(awm[i], bmh, a, 0, 0, 0);
        am[s][i] = a;
        int o0 = (mh*3 + i)*16 + kq*4;
        *(u32*)&sm.xh[s][swx(lr, o0)]     = f2b2(a[0], a[1]);   // next step's x
        *(u32*)&sm.xh[s][swx(lr, o0 + 2)] = f2b2(a[2], a[3]);
      }
    }
    __builtin_amdgcn_s_setprio(0);
    BARRIER_NOVM();   // B5: next x visible for P1(t+1)
    // ---- global stores AFTER barrier: never drained in-loop ----
    #pragma unroll
    for (int s = 0; s < 2; ++s){
      float* outb = out + (size_t)t*BATCH*96 + (size_t)(ebase + s*16 + lr)*96;
      #pragma unroll
      for (int i = 0; i < 3; ++i){
        int o0 = (mh*3 + i)*16 + kq*4;
        *(f32x4*)(outb + o0) = am[s][i];
      }
    }
  }
}

extern "C" void kernel_launch(void* const* d_in, const int* in_sizes, int n_in,
                              void* d_out, int out_size, void* d_ws, size_t ws_size,
                              hipStream_t stream){
  decoder_kernel<<<dim3(BATCH/ET), dim3(128), 0, stream>>>(
      (const float*)d_in[0],  (const float*)d_in[1],
      (const float*)d_in[3],  (const float*)d_in[4],
      (const float*)d_in[5],  (const float*)d_in[6],
      (const float*)d_in[7],  (const float*)d_in[8],
      (const float*)d_in[9],  (const float*)d_in[10],
      (const float*)d_in[11], (const float*)d_in[12],
      (const float*)d_in[13], (const float*)d_in[14],
      (float*)d_out);
}